// Round 2
// baseline (308.775 us; speedup 1.0000x reference)
//
#include <hip/hip_runtime.h>
#include <cmath>

#define NLVL 16
#define TSIZE (1u << 19)
#define HMASK ((1u << 19) - 1u)
#define PRIME1 2654435761u

struct ResParams { float rf[NLVL]; int ri[NLVL]; };

__device__ __forceinline__ float2 selhalf(float4 v, unsigned odd) {
    return odd ? make_float2(v.z, v.w) : make_float2(v.x, v.y);
}

// Gather-transaction-bound kernel. Key trick: x-corner pair (cx0, cx0+1)
// hashes to the SAME aligned float4 pair {A&~1, A|1} whenever cx0 is even
// (xor with row-hash preserves pair index), so one float4 load covers both
// corners ~50% of the time; the second load is exec-masked divergent.
__global__ __launch_bounds__(256, 4) void hash_embed(
    const float2* __restrict__ x,
    const float4* __restrict__ emb4,   // table viewed as aligned float2-pairs
    float* __restrict__ out,
    ResParams rp, int n)
{
    __shared__ float2 lds[NLVL * 256];   // [level][tid], 32 KiB
    const int tid = threadIdx.x;
    const int i = blockIdx.x * 256 + tid;
    float2 xy = make_float2(0.f, 0.f);
    if (i < n) xy = x[i];

    #pragma unroll
    for (int batch = 0; batch < 4; ++batch) {
        float4 A[8], B[8];
        unsigned flags[8];           // bit0: ad0 parity, bit1: ad1 parity, bit2: pair differs
        float w0v[4], w1v[4];
        // phase 1: addresses + issue loads for 4 levels (8 rows)
        #pragma unroll
        for (int j = 0; j < 4; ++j) {
            const int l = batch * 4 + j;
            const float rf = rp.rf[l];
            const int ri = rp.ri[l];
            const float px = xy.x * rf, py = xy.y * rf;
            const float fx = floorf(px), fy = floorf(py);
            w0v[j] = px - fx;
            w1v[j] = py - fy;
            const int tx = (int)fx, ty = (int)fy;
            const unsigned cx0 = (unsigned)min(tx, ri);
            const unsigned cx1 = (unsigned)min(tx + 1, ri);
            const unsigned hy0 = (unsigned)min(ty, ri) * PRIME1;
            const unsigned hy1 = (unsigned)min(ty + 1, ri) * PRIME1;
            const float4* tab4 = emb4 + (size_t)l * (TSIZE / 2);
            #pragma unroll
            for (int r = 0; r < 2; ++r) {
                const unsigned hy = r ? hy1 : hy0;
                const unsigned ad0 = (cx0 ^ hy) & HMASK;
                const unsigned ad1 = (cx1 ^ hy) & HMASK;
                const int k = j * 2 + r;
                const unsigned diff = (ad1 >> 1) != (ad0 >> 1);
                flags[k] = (ad0 & 1u) | ((ad1 & 1u) << 1) | (diff << 2);
                A[k] = tab4[ad0 >> 1];
                B[k] = make_float4(0.f, 0.f, 0.f, 0.f);
                if (diff)                      // divergent: exec-masked load,
                    B[k] = tab4[ad1 >> 1];     // ~32/64 lanes → ~half the TA cost
            }
        }
        // phase 2: select corners, bilinear blend, stash to LDS
        #pragma unroll
        for (int j = 0; j < 4; ++j) {
            const int l = batch * 4 + j;
            const float w0 = w0v[j], w1 = w1v[j];
            const float u0 = 1.f - w0, u1 = 1.f - w1;
            float2 c[4];
            #pragma unroll
            for (int r = 0; r < 2; ++r) {
                const int k = j * 2 + r;
                const unsigned fl = flags[k];
                const float2 e0 = selhalf(A[k], fl & 1u);
                const float4 s1 = (fl & 4u) ? B[k] : A[k];
                const float2 e1 = selhalf(s1, (fl >> 1) & 1u);
                c[r * 2 + 0] = e0;
                c[r * 2 + 1] = e1;
            }
            const float g0 = (c[0].x*u0 + c[1].x*w0)*u1 + (c[2].x*u0 + c[3].x*w0)*w1;
            const float g1 = (c[0].y*u0 + c[1].y*w0)*u1 + (c[2].y*u0 + c[3].y*w0)*w1;
            lds[l * 256 + tid] = make_float2(g0, g1);
        }
    }
    __syncthreads();

    // coalesced write-out: block covers out[block*8192 .. +8192)
    const float* lf = (const float*)lds;  // [l][tid][c]
    const long long total = (long long)n * 32;
    const long long base = (long long)blockIdx.x * 8192;
    #pragma unroll
    for (int it = 0; it < 8; ++it) {
        const int k = (it * 256 + tid) * 4;   // float offset within block region
        if (base + k < total) {
            const int p = k >> 5;         // point within block
            const int f0i = k & 31;       // feature index (multiple of 4)
            const int l0 = f0i >> 1;      // covers levels l0, l0+1 (both feats)
            float4 v;
            v.x = lf[(l0 * 256 + p) * 2 + 0];
            v.y = lf[(l0 * 256 + p) * 2 + 1];
            v.z = lf[((l0 + 1) * 256 + p) * 2 + 0];
            v.w = lf[((l0 + 1) * 256 + p) * 2 + 1];
            *(float4*)(out + base + k) = v;
        }
    }
}

extern "C" void kernel_launch(void* const* d_in, const int* in_sizes, int n_in,
                              void* d_out, int out_size, void* d_ws, size_t ws_size,
                              hipStream_t stream) {
    const float2* x = (const float2*)d_in[0];
    const float4* emb4 = (const float4*)d_in[1];
    float* out = (float*)d_out;
    const int n = in_sizes[0] / 2;

    // Replicate numpy's exact double-precision chain for the per-level
    // resolutions; floor decisions at l=3,6,9,12,15 are ulp-sensitive.
    ResParams rp;
    const double b = std::exp((std::log(512.0) - std::log(16.0)) / 15.0);
    for (int l = 0; l < NLVL; ++l) {
        const double r = std::floor(16.0 * std::pow(b, (double)l));
        rp.rf[l] = (float)r;
        rp.ri[l] = (int)r;
    }

    const int grid = (n + 255) / 256;
    hash_embed<<<grid, 256, 0, stream>>>(x, emb4, out, rp, n);
}

// Round 3
// 282.359 us; speedup vs baseline: 1.0936x; 1.0936x over previous
//
#include <hip/hip_runtime.h>
#include <cmath>

#define NLVL 16
#define TSIZE (1u << 19)
#define HMASK ((1u << 19) - 1u)
#define PRIME1 2654435761u

struct Params {
    float rf[NLVL];
    int   ri[NLVL];
    int   base[NLVL];     // float2 index of level's dense table inside ws
    int   stride[NLVL];   // ri+2 (one pad entry per row so float4@cx0 is in-bounds)
};

// Pre-pass: un-hash each level's accessed window [0,res]^2 into a dense,
// spatially-local table. 712K cells = 5.45 MiB total. Runs every launch.
__global__ __launch_bounds__(256) void build_dense(
    const float2* __restrict__ emb, float2* __restrict__ dense, Params p)
{
    const int l = blockIdx.y;
    const int cy = blockIdx.x;
    const int ri = p.ri[l];
    if (cy > ri) return;
    const unsigned hy = (unsigned)cy * PRIME1;
    const float2* tab = emb + (size_t)l * TSIZE;
    float2* drow = dense + p.base[l] + (size_t)cy * p.stride[l];
    for (int cx = threadIdx.x; cx <= ri; cx += 256)
        drow[cx] = tab[((unsigned)cx ^ hy) & HMASK];
}

// Main: per level, ONE float4 row-load covers both x-corners (adjacent in the
// dense layout) -> 32 load instructions/point instead of 64, on a 5.45 MB
// L2-resident footprint instead of 64 MB hash tables.
__global__ __launch_bounds__(256) void hash_embed_dense(
    const float2* __restrict__ x,
    const float2* __restrict__ dense,
    float* __restrict__ out,
    Params p, int n)
{
    __shared__ float2 lds[NLVL * 256];   // [level][tid], 32 KiB
    const int tid = threadIdx.x;
    const int i = blockIdx.x * 256 + tid;
    float2 xy = make_float2(0.f, 0.f);
    if (i < n) xy = x[i];

    #pragma unroll
    for (int half = 0; half < 2; ++half) {
        float4 r0[8], r1[8];
        float w0v[8], w1v[8];
        int edge[8];
        // phase 1: addresses + issue 16 row-loads
        #pragma unroll
        for (int j = 0; j < 8; ++j) {
            const int l = half * 8 + j;
            const float rf = p.rf[l];
            const int ri = p.ri[l];
            const float px = xy.x * rf, py = xy.y * rf;
            const float fx = floorf(px), fy = floorf(py);
            w0v[j] = px - fx;
            w1v[j] = py - fy;
            const int tx = (int)fx, ty = (int)fy;
            const int cx0 = min(tx, ri);          // px can round to exactly res
            const int cy0 = min(ty, ri);
            const int cy1 = min(ty + 1, ri);
            edge[j] = (cx0 == ri);                // then cx1==cx0 (clip)
            const float2* tab = dense + p.base[l];
            const float2* a0 = tab + cy0 * p.stride[l] + cx0;
            const float2* a1 = tab + cy1 * p.stride[l] + cx0;
            __builtin_memcpy(&r0[j], a0, 16);     // 8B-aligned 16B load (dwordx4)
            __builtin_memcpy(&r1[j], a1, 16);
        }
        // phase 2: bilinear blend (reference order), stash to LDS
        #pragma unroll
        for (int j = 0; j < 8; ++j) {
            const int l = half * 8 + j;
            const float w0 = w0v[j], w1 = w1v[j];
            const float u0 = 1.f - w0, u1 = 1.f - w1;
            const float e00x = r0[j].x, e00y = r0[j].y;
            const float e01x = edge[j] ? r0[j].x : r0[j].z;
            const float e01y = edge[j] ? r0[j].y : r0[j].w;
            const float e10x = r1[j].x, e10y = r1[j].y;
            const float e11x = edge[j] ? r1[j].x : r1[j].z;
            const float e11y = edge[j] ? r1[j].y : r1[j].w;
            const float g0 = (e00x*u0 + e01x*w0)*u1 + (e10x*u0 + e11x*w0)*w1;
            const float g1 = (e00y*u0 + e01y*w0)*u1 + (e10y*u0 + e11y*w0)*w1;
            lds[l * 256 + tid] = make_float2(g0, g1);
        }
    }
    __syncthreads();

    // coalesced write-out: block covers out[block*8192 .. +8192)
    const float* lf = (const float*)lds;  // [l][tid][c]
    const long long total = (long long)n * 32;
    const long long base = (long long)blockIdx.x * 8192;
    #pragma unroll
    for (int it = 0; it < 8; ++it) {
        const int k = (it * 256 + tid) * 4;
        if (base + k < total) {
            const int p2 = k >> 5;
            const int l0 = (k & 31) >> 1;
            float4 v;
            v.x = lf[(l0 * 256 + p2) * 2 + 0];
            v.y = lf[(l0 * 256 + p2) * 2 + 1];
            v.z = lf[((l0 + 1) * 256 + p2) * 2 + 0];
            v.w = lf[((l0 + 1) * 256 + p2) * 2 + 1];
            *(float4*)(out + base + k) = v;
        }
    }
}

// Fallback (round-1 kernel): direct hash gathers, used only if ws is too small.
__global__ __launch_bounds__(256) void hash_embed_direct(
    const float2* __restrict__ x,
    const float2* __restrict__ emb,
    float* __restrict__ out,
    Params p, int n)
{
    __shared__ float2 lds[NLVL * 256];
    const int tid = threadIdx.x;
    const int i = blockIdx.x * 256 + tid;
    float2 xy = make_float2(0.f, 0.f);
    if (i < n) xy = x[i];

    #pragma unroll
    for (int half = 0; half < 2; ++half) {
        float2 f[32];
        float w0v[8], w1v[8];
        #pragma unroll
        for (int j = 0; j < 8; ++j) {
            const int l = half * 8 + j;
            const float rf = p.rf[l];
            const int ri = p.ri[l];
            const float px = xy.x * rf, py = xy.y * rf;
            const float fx = floorf(px), fy = floorf(py);
            w0v[j] = px - fx;
            w1v[j] = py - fy;
            const int tx = (int)fx, ty = (int)fy;
            const unsigned cx0 = (unsigned)min(tx, ri);
            const unsigned cy0 = (unsigned)min(ty, ri);
            const unsigned cx1 = (unsigned)min(tx + 1, ri);
            const unsigned cy1 = (unsigned)min(ty + 1, ri);
            const unsigned hy0 = cy0 * PRIME1;
            const unsigned hy1 = cy1 * PRIME1;
            const float2* tab = emb + (size_t)l * TSIZE;
            f[j*4+0] = tab[(cx0 ^ hy0) & HMASK];
            f[j*4+1] = tab[(cx1 ^ hy0) & HMASK];
            f[j*4+2] = tab[(cx0 ^ hy1) & HMASK];
            f[j*4+3] = tab[(cx1 ^ hy1) & HMASK];
        }
        #pragma unroll
        for (int j = 0; j < 8; ++j) {
            const int l = half * 8 + j;
            const float w0 = w0v[j], w1 = w1v[j];
            const float u0 = 1.f - w0, u1 = 1.f - w1;
            const float2 f0 = f[j*4+0], f1 = f[j*4+1], f2 = f[j*4+2], f3 = f[j*4+3];
            const float g0 = (f0.x*u0 + f1.x*w0)*u1 + (f2.x*u0 + f3.x*w0)*w1;
            const float g1 = (f0.y*u0 + f1.y*w0)*u1 + (f2.y*u0 + f3.y*w0)*w1;
            lds[l * 256 + tid] = make_float2(g0, g1);
        }
    }
    __syncthreads();

    const float* lf = (const float*)lds;
    const long long total = (long long)n * 32;
    const long long base = (long long)blockIdx.x * 8192;
    #pragma unroll
    for (int it = 0; it < 8; ++it) {
        const int k = (it * 256 + tid) * 4;
        if (base + k < total) {
            const int p2 = k >> 5;
            const int l0 = (k & 31) >> 1;
            float4 v;
            v.x = lf[(l0 * 256 + p2) * 2 + 0];
            v.y = lf[(l0 * 256 + p2) * 2 + 1];
            v.z = lf[((l0 + 1) * 256 + p2) * 2 + 0];
            v.w = lf[((l0 + 1) * 256 + p2) * 2 + 1];
            *(float4*)(out + base + k) = v;
        }
    }
}

extern "C" void kernel_launch(void* const* d_in, const int* in_sizes, int n_in,
                              void* d_out, int out_size, void* d_ws, size_t ws_size,
                              hipStream_t stream) {
    const float2* x = (const float2*)d_in[0];
    const float2* emb = (const float2*)d_in[1];
    float* out = (float*)d_out;
    const int n = in_sizes[0] / 2;

    // numpy-exact per-level resolutions (ulp-sensitive floors at l=3,6,9,...)
    Params p;
    int off = 0;
    const double b = std::exp((std::log(512.0) - std::log(16.0)) / 15.0);
    for (int l = 0; l < NLVL; ++l) {
        const double r = std::floor(16.0 * std::pow(b, (double)l));
        p.rf[l] = (float)r;
        p.ri[l] = (int)r;
        p.stride[l] = p.ri[l] + 2;
        p.base[l] = off;
        off += (p.ri[l] + 1) * (p.ri[l] + 2);
    }
    const size_t need = (size_t)off * sizeof(float2);   // ~5.45 MiB

    const int grid = (n + 255) / 256;
    if (ws_size >= need) {
        build_dense<<<dim3(513, 16), 256, 0, stream>>>(emb, (float2*)d_ws, p);
        hash_embed_dense<<<grid, 256, 0, stream>>>(x, (const float2*)d_ws, out, p, n);
    } else {
        hash_embed_direct<<<grid, 256, 0, stream>>>(x, emb, out, p, n);
    }
}